// Round 1
// baseline (282.577 us; speedup 1.0000x reference)
//
#include <hip/hip_runtime.h>
#include <math.h>

#define NN 1024     // entities
#define HD 128      // hidden dim
#define NH 8        // heads
#define CH 16       // dim per head
#define NLAYERS 3

#define ST 1032     // s_tile row stride in floats: 1032 % 32 == 8 -> exact 2-way LDS aliasing (free)

// ---------------- K1: a = x@W1[:128], b = x@W1[128:] + b1 ----------------
__global__ __launch_bounds__(256) void k_edge_ab(
        const float* __restrict__ x, const float* __restrict__ W1,
        const float* __restrict__ b1, float* __restrict__ a, float* __restrict__ b) {
    __shared__ float xr[HD];
    const int row = blockIdx.x, t = threadIdx.x;
    if (t < HD) xr[t] = x[row * HD + t];
    __syncthreads();
    const int c = t & 127;
    const int half = t >> 7;                 // 0 -> a, 1 -> b
    const float* w = W1 + half * HD * HD + c;
    float acc = half ? b1[c] : 0.f;          // fold b1 into b
    #pragma unroll 8
    for (int kk = 0; kk < HD; ++kk) acc = fmaf(xr[kk], w[kk * HD], acc);
    (half ? b : a)[row * HD + c] = acc;
}

// ---------------- K2: wm[t][s] = sign(mask) * sigmoid(logit[s][t]) ----------------
// logit[s][t] = sum_h relu(a[s][h] + bb[t][h]) * W2[h] + b2   (bb already includes b1)
__global__ __launch_bounds__(256) void k_edge_w(
        const float* __restrict__ a, const float* __restrict__ bb,
        const float* __restrict__ W2, const float* __restrict__ b2,
        float* __restrict__ wm) {
    __shared__ float al[32][HD + 1];   // +1 pad: lanes s=0..31 read al[s][h] -> distinct banks
    __shared__ float bl[16][HD];       // broadcast reads
    __shared__ float w2[HD];
    const int t = threadIdx.x;
    const int s0 = blockIdx.x * 32, t0 = blockIdx.y * 16;
    for (int i = t; i < 32 * HD; i += 256) al[i >> 7][i & 127] = a[(s0 + (i >> 7)) * HD + (i & 127)];
    for (int i = t; i < 16 * HD; i += 256) bl[i >> 7][i & 127] = bb[(t0 + (i >> 7)) * HD + (i & 127)];
    if (t < HD) w2[t] = W2[t];
    __syncthreads();
    const int s = t & 31, tt = t >> 5;      // each thread: source s, targets {tt, tt+8}
    float acc0 = 0.f, acc1 = 0.f;
    #pragma unroll 4
    for (int h = 0; h < HD; ++h) {
        const float av = al[s][h], wv = w2[h];
        acc0 = fmaf(fmaxf(av + bl[tt][h],     0.f), wv, acc0);
        acc1 = fmaf(fmaxf(av + bl[tt + 8][h], 0.f), wv, acc1);
    }
    const float bias = b2[0];
    const float l0 = acc0 + bias, l1 = acc1 + bias;
    const float w0 = 1.f / (1.f + __expf(-l0));
    const float w1 = 1.f / (1.f + __expf(-l1));
    wm[(t0 + tt    ) * NN + s0 + s] = (l0 > 0.f) ? w0 : -w0;   // sign encodes mask
    wm[(t0 + tt + 8) * NN + s0 + s] = (l1 > 0.f) ? w1 : -w1;
}

// ---------------- K3: per-layer projections q,k,v (in [h][n][c] layout) + skip ----------------
__global__ __launch_bounds__(256) void k_proj(
        const float* __restrict__ x,
        const float* __restrict__ Wq, const float* __restrict__ bq,
        const float* __restrict__ Wk, const float* __restrict__ bk,
        const float* __restrict__ Wv, const float* __restrict__ bv,
        const float* __restrict__ Wsk, const float* __restrict__ bsk,
        float* __restrict__ q, float* __restrict__ k,
        float* __restrict__ v, float* __restrict__ skip) {
    __shared__ float xr[HD];
    const int row = blockIdx.x, t = threadIdx.x;
    if (t < HD) xr[t] = x[row * HD + t];
    __syncthreads();
    const int c = t & 127;
    const bool lo = t < 128;                   // lo: q&k columns, hi: v&skip columns
    const float* WA = lo ? Wq : Wv;
    const float* WB = lo ? Wk : Wsk;
    float a0 = lo ? bq[c] : bv[c];
    float a1 = lo ? bk[c] : bsk[c];
    #pragma unroll 8
    for (int kk = 0; kk < HD; ++kk) {
        const float xv = xr[kk];
        a0 = fmaf(xv, WA[kk * HD + c], a0);
        a1 = fmaf(xv, WB[kk * HD + c], a1);
    }
    const int hnc = (c >> 4) * (NN * CH) + row * CH + (c & 15);
    if (lo) { q[hnc] = a0; k[hnc] = a1; }
    else    { v[hnc] = a0; skip[row * HD + c] = a1; }
}

// ---------------- K4: fused attention for one (head, 16-target tile); x updated in place ----------------
__global__ __launch_bounds__(256) void k_attn(
        const float* __restrict__ q, const float* __restrict__ k,
        const float* __restrict__ v, const float* __restrict__ skip,
        const float* __restrict__ wm, const float* __restrict__ We,
        float* __restrict__ x) {
    __shared__ float s_tile[16][ST];   // ~66 KB -> 2 blocks/CU
    __shared__ float q_l[16][CH];      // q * 0.25 (scale folded)
    __shared__ float we_l[CH];
    __shared__ float qwe_l[16];
    const int h  = blockIdx.x;
    const int i0 = blockIdx.y * 16;
    const int t  = threadIdx.x;
    {
        const int i = t >> 4, c = t & 15;
        q_l[i][c] = q[h * (NN * CH) + (i0 + i) * CH + c] * 0.25f;
        if (t < CH) we_l[t] = We[h * CH + t];
    }
    __syncthreads();
    if (t < 16) {
        float sv = 0.f;
        #pragma unroll
        for (int c = 0; c < CH; ++c) sv = fmaf(q_l[t][c], we_l[c], sv);
        qwe_l[t] = sv;                 // already carries the 0.25 scale
    }
    __syncthreads();

    // phase 1: logits. thread t handles j = t + 256*rep for all 16 targets.
    const float* kh = k + h * (NN * CH);
    for (int rep = 0; rep < 4; ++rep) {
        const int j = t + rep * 256;
        float kr[CH];
        #pragma unroll
        for (int c = 0; c < CH; ++c) kr[c] = kh[j * CH + c];
        #pragma unroll
        for (int i = 0; i < 16; ++i) {
            float dot = 0.f;
            #pragma unroll
            for (int c = 0; c < CH; ++c) dot = fmaf(q_l[i][c], kr[c], dot);
            const float wv = wm[(i0 + i) * NN + j];          // sign = mask
            const float sv = dot + qwe_l[i] * fabsf(wv);
            s_tile[i][j] = (wv > 0.f) ? sv : -1e30f;
        }
    }
    __syncthreads();

    // phase 2: masked softmax per row. 16 threads per row, interleaved scan.
    const int i = t >> 4, slot = t & 15;
    float m = -1e30f;
    #pragma unroll 8
    for (int jj = 0; jj < 64; ++jj) m = fmaxf(m, s_tile[i][slot + 16 * jj]);
    #pragma unroll
    for (int off = 1; off < 16; off <<= 1) m = fmaxf(m, __shfl_xor(m, off));
    const float* wrow = wm + (i0 + i) * NN;
    float sum = 0.f, aw = 0.f;
    #pragma unroll 4
    for (int jj = 0; jj < 64; ++jj) {
        const int j = slot + 16 * jj;
        const float sv = s_tile[i][j];
        const float p = (sv > -1e29f) ? __expf(sv - m) : 0.f;
        s_tile[i][j] = p;
        sum += p;
        aw = fmaf(p, fabsf(wrow[j]), aw);
    }
    #pragma unroll
    for (int off = 1; off < 16; off <<= 1) {
        sum += __shfl_xor(sum, off);
        aw  += __shfl_xor(aw, off);
    }
    const float inv = (m > -1e29f) ? 1.f / sum : 0.f;   // all-masked row -> output 0
    aw *= inv;
    __syncthreads();

    // phase 3: out[i][c] = inv * sum_j p[i][j] * v[h][j][c]; thread owns (i, c=slot).
    const float* vh = v + h * (NN * CH) + slot;
    float a0 = 0.f, a1 = 0.f, a2 = 0.f, a3 = 0.f;
    for (int j = 0; j < NN; j += 4) {
        a0 = fmaf(s_tile[i][j + 0], vh[(j + 0) * CH], a0);
        a1 = fmaf(s_tile[i][j + 1], vh[(j + 1) * CH], a1);
        a2 = fmaf(s_tile[i][j + 2], vh[(j + 2) * CH], a2);
        a3 = fmaf(s_tile[i][j + 3], vh[(j + 3) * CH], a3);
    }
    const float outv = (a0 + a1 + a2 + a3) * inv + aw * we_l[slot];
    const int idx = (i0 + i) * HD + h * CH + slot;
    x[idx] = x[idx] + outv + skip[idx];   // residual + skip; slice owned exclusively by this block
}

// ---------------- launch ----------------
extern "C" void kernel_launch(void* const* d_in, const int* in_sizes, int n_in,
                              void* d_out, int out_size, void* d_ws, size_t ws_size,
                              hipStream_t stream) {
    const float* ent = (const float*)d_in[2];
    const float* W1  = (const float*)d_in[3];
    const float* b1  = (const float*)d_in[4];
    const float* W2  = (const float*)d_in[5];
    const float* b2  = (const float*)d_in[6];
    const float* Wq  = (const float*)d_in[7];
    const float* bq  = (const float*)d_in[8];
    const float* Wk  = (const float*)d_in[9];
    const float* bk  = (const float*)d_in[10];
    const float* Wv  = (const float*)d_in[11];
    const float* bv  = (const float*)d_in[12];
    const float* We  = (const float*)d_in[13];
    const float* Ws  = (const float*)d_in[14];
    const float* bs  = (const float*)d_in[15];

    float* ws = (float*)d_ws;
    float* wm = ws;                        // [1024][1024]  signed w (mask in sign)
    float* q  = ws + NN * NN;              // [8][1024][16]  (reused as 'a' before layers)
    float* k  = q  + NN * HD;              //                (reused as 'b')
    float* v  = k  + NN * HD;
    float* sk = v  + NN * HD;
    float* x  = (float*)d_out;             // running entity state

    // x <- entity_embeddings
    hipMemcpyAsync(x, ent, NN * HD * sizeof(float), hipMemcpyDeviceToDevice, stream);

    // edge graph (built once from initial embeddings)
    k_edge_ab<<<NN, 256, 0, stream>>>(ent, W1, b1, q /*a*/, k /*b*/);
    k_edge_w<<<dim3(32, 64), 256, 0, stream>>>(q, k, W2, b2, wm);

    for (int l = 0; l < NLAYERS; ++l) {
        k_proj<<<NN, 256, 0, stream>>>(x,
            Wq + l * HD * HD, bq + l * HD, Wk + l * HD * HD, bk + l * HD,
            Wv + l * HD * HD, bv + l * HD, Ws + l * HD * HD, bs + l * HD,
            q, k, v, sk);
        k_attn<<<dim3(NH, 64), 256, 0, stream>>>(q, k, v, sk, wm, We + l * HD, x);
    }
}